// Round 8
// baseline (242.078 us; speedup 1.0000x reference)
//
#include <hip/hip_runtime.h>

// GuidedFilterND: I (8,4,768,768) f32 guide, p (8,1,768,768) f32 input, r=8, eps=1e-4.
// Stage A: box-filter 19 product channels, per-pixel 4x4 SPD solve -> (As,b) float2 + sumI (ws)
// Stage B: box-filter (As,b); q = (f(As)*sumI + f(b)) / N
// Round 8: stage A = round-5 exact (SHA=24; SHA=12 regressed: occupancy is LDS-capped
//          at 7 blocks/CU, smaller stripes only add warm-up).  Stage B rewritten as
//          BARRIER-FREE wave-synchronous kernel: vertical rolling sums per lane,
//          horizontal 17-tap via cross-lane shuffles (s4 trick: 7 shfl/channel).
//          Three prior LDS+barrier stage Bs all cost ~110-120 us; this removes the
//          hypothesized limiter (per-row barrier serialization) entirely.

#define HH 768
#define WW 768
#define CC 4
#define BB 8
#define RR 8
#define EPSF 1.0e-4f

#define TA 128      // stage A threads per block
#define OUTA 112    // output columns per block (TA - 2*RR)
#define SHA 24      // stage A rows per stripe
#define NSTRIPE (HH / SHA)    // 32
#define NBAND 7               // ceil(768/112)

// stage B wave geometry
#define OBW 48                // output columns per wave
#define NBANDB (WW / OBW)     // 16
#define SHBR 32               // rows per wave stripe
#define NSTRIPB (HH / SHBR)   // 24
#define UNITS (NBANDB * NSTRIPB * BB)   // 3072 wave-units
#define TBB 256               // 4 waves per block

__device__ __forceinline__ void loadpix(const float* __restrict__ Ib,
                                        const float* __restrict__ pb,
                                        int row, int gc, float pr[19]) {
  const int off = row * WW + gc;
  const int chs = HH * WW;
  float i0 = Ib[off];
  float i1 = Ib[chs + off];
  float i2 = Ib[2 * chs + off];
  float i3 = Ib[3 * chs + off];
  float pv = pb[off];
  pr[0] = i0; pr[1] = i1; pr[2] = i2; pr[3] = i3;
  pr[4] = pv;
  pr[5] = pv * i0; pr[6] = pv * i1; pr[7] = pv * i2; pr[8] = pv * i3;
  pr[9]  = i0 * i0; pr[10] = i0 * i1; pr[11] = i0 * i2; pr[12] = i0 * i3;
  pr[13] = i1 * i1; pr[14] = i1 * i2; pr[15] = i1 * i3;
  pr[16] = i2 * i2; pr[17] = i2 * i3;
  pr[18] = i3 * i3;
}

__global__ __launch_bounds__(TA) void gf_stageA(const float* __restrict__ I,
                                                const float* __restrict__ p,
                                                float2* __restrict__ AB,
                                                float* __restrict__ sumI_ws,
                                                int storeSum) {
  // thread-major, padded to 20 floats (80 B): b128 accesses, conflict-free
  __shared__ float v[TA][20];
  __shared__ float s4[TA][20];
  const int tid = threadIdx.x;
  const int band0 = (int)blockIdx.x * OUTA;
  const int r0 = (int)blockIdx.y * SHA;
  const int batch = (int)blockIdx.z;
  const int gc = band0 - RR + tid;            // column this thread's vertical sum covers
  const bool colok = (gc >= 0 && gc < WW);

  const float* Ib = I + (size_t)batch * CC * HH * WW;
  const float* pb = p + (size_t)batch * HH * WW;
  float* sIb = sumI_ws + (size_t)batch * HH * WW;

  float s[20];
#pragma unroll
  for (int k = 0; k < 20; ++k) s[k] = 0.0f;

  // warm-up: preload window of row (r0-1) = rows [r0-RR-1, r0+RR-1] clipped.
  if (colok) {
    int rlo = r0 - RR - 1; if (rlo < 0) rlo = 0;
    for (int row = rlo; row < r0 + RR; ++row) {
      float pr[19]; loadpix(Ib, pb, row, gc, pr);
#pragma unroll
      for (int k = 0; k < 19; ++k) s[k] += pr[k];
      // rows 0..7 are only ever touched by stripe 0's warm-up: store sumI here
      if (storeSum && r0 == 0)
        sIb[row * WW + gc] = pr[0] + pr[1] + pr[2] + pr[3];
    }
  }

  const int oc = band0 + tid;                 // output column for threads < OUTA
  const bool outok = (tid < OUTA) && (oc < WW);
  const int nw = min(oc + RR, WW - 1) - max(oc - RR, 0) + 1;

  for (int r = r0; r < r0 + SHA; ++r) {
    if (colok) {
      int rl = r + RR;
      if (rl < HH) {
        float pr[19]; loadpix(Ib, pb, rl, gc, pr);
#pragma unroll
        for (int k = 0; k < 19; ++k) s[k] += pr[k];
        if (storeSum)
          sIb[rl * WW + gc] = pr[0] + pr[1] + pr[2] + pr[3];
      }
      int rt = r - RR - 1;
      if (rt >= 0) {
        float pr[19]; loadpix(Ib, pb, rt, gc, pr);
#pragma unroll
        for (int k = 0; k < 19; ++k) s[k] -= pr[k];
      }
    }
    // publish vertical sums: 5 x b128 writes
    {
      float4* vp = (float4*)(&v[tid][0]);
      vp[0] = make_float4(s[0],  s[1],  s[2],  s[3]);
      vp[1] = make_float4(s[4],  s[5],  s[6],  s[7]);
      vp[2] = make_float4(s[8],  s[9],  s[10], s[11]);
      vp[3] = make_float4(s[12], s[13], s[14], s[15]);
      vp[4] = make_float4(s[16], s[17], s[18], 0.0f);
    }
    __syncthreads();
    float t4[20];
    if (tid < TA - 3) {
      const float* a1 = &v[tid + 1][0];
      const float* a2 = &v[tid + 2][0];
      const float* a3 = &v[tid + 3][0];
      float4* op = (float4*)(&s4[tid][0]);
#pragma unroll
      for (int j = 0; j < 5; ++j) {
        float4 xa = ((const float4*)a1)[j];
        float4 xb = ((const float4*)a2)[j];
        float4 xc = ((const float4*)a3)[j];
        float o0 = s[4*j + 0] + xa.x + xb.x + xc.x;
        float o1 = s[4*j + 1] + xa.y + xb.y + xc.y;
        float o2 = s[4*j + 2] + xa.z + xb.z + xc.z;
        float o3 = s[4*j + 3] + xa.w + xb.w + xc.w;
        op[j] = make_float4(o0, o1, o2, o3);
        t4[4*j + 0] = o0; t4[4*j + 1] = o1; t4[4*j + 2] = o2; t4[4*j + 3] = o3;
      }
    }
    __syncthreads();
    if (outok) {
      float h[20];
      const float* q4  = &s4[tid + 4][0];
      const float* q8  = &s4[tid + 8][0];
      const float* q12 = &s4[tid + 12][0];
      const float* q16 = &v[tid + 16][0];
#pragma unroll
      for (int j = 0; j < 5; ++j) {
        float4 a4 = ((const float4*)q4)[j];
        float4 b4 = ((const float4*)q8)[j];
        float4 c4 = ((const float4*)q12)[j];
        float4 d4 = ((const float4*)q16)[j];
        h[4*j + 0] = t4[4*j + 0] + a4.x + b4.x + c4.x + d4.x;
        h[4*j + 1] = t4[4*j + 1] + a4.y + b4.y + c4.y + d4.y;
        h[4*j + 2] = t4[4*j + 2] + a4.z + b4.z + c4.z + d4.z;
        h[4*j + 3] = t4[4*j + 3] + a4.w + b4.w + c4.w + d4.w;
      }
      const int nh = min(r + RR, HH - 1) - max(r - RR, 0) + 1;
      const float invN = 1.0f / (float)(nh * nw);
      float Im0 = h[0] * invN, Im1 = h[1] * invN, Im2 = h[2] * invN, Im3 = h[3] * invN;
      float pm = h[4] * invN;
      float ft0 = h[5] * invN - pm * Im0;
      float ft1 = h[6] * invN - pm * Im1;
      float ft2 = h[7] * invN - pm * Im2;
      float ft3 = h[8] * invN - pm * Im3;
      float m[4][4];
      m[0][0] = h[9]  * invN + EPSF;
      m[0][1] = h[10] * invN;
      m[0][2] = h[11] * invN;
      m[0][3] = h[12] * invN;
      m[1][1] = h[13] * invN + EPSF;
      m[1][2] = h[14] * invN;
      m[1][3] = h[15] * invN;
      m[2][2] = h[16] * invN + EPSF;
      m[2][3] = h[17] * invN;
      m[3][3] = h[18] * invN + EPSF;
      m[1][0] = m[0][1]; m[2][0] = m[0][2]; m[3][0] = m[0][3];
      m[2][1] = m[1][2]; m[3][1] = m[1][3]; m[3][2] = m[2][3];
      float y[4] = {1.0f, 1.0f, 1.0f, 1.0f};
#pragma unroll
      for (int k = 0; k < 4; ++k) {
        float piv = 1.0f / m[k][k];
#pragma unroll
        for (int j = 0; j < 4; ++j) m[k][j] *= piv;
        y[k] *= piv;
#pragma unroll
        for (int i = 0; i < 4; ++i) {
          if (i == k) continue;
          float f = m[i][k];
#pragma unroll
          for (int j = 0; j < 4; ++j) m[i][j] -= f * m[k][j];
          y[i] -= f * y[k];
        }
      }
      float Asum = ft0 * y[0] + ft1 * y[1] + ft2 * y[2] + ft3 * y[3];
      float bv = pm - Asum * (Im0 + Im1 + Im2 + Im3);
      AB[((size_t)batch * HH + r) * WW + oc] = make_float2(Asum, bv);
    }
    __syncthreads();
  }
}

// Stage B: barrier-free wave-synchronous box filter.
// One wave owns a 48-col x 32-row output stripe. Lane l carries the vertical
// rolling sum of column band0-8+l; the 17-tap horizontal sum is built from
// cross-lane shuffles only (no LDS arrays, no __syncthreads).
__global__ __launch_bounds__(TBB) void gf_stageB(const float* __restrict__ I,
                                                 const float2* __restrict__ AB,
                                                 const float* __restrict__ sumI_ws,
                                                 float* __restrict__ q, int useSum) {
  const int lane = threadIdx.x & 63;
  const int wid  = threadIdx.x >> 6;
  const int unit = (int)blockIdx.x * 4 + wid;          // 0..UNITS-1
  const int band   = unit & (NBANDB - 1);              // 16 bands
  const int stripe = (unit >> 4) % NSTRIPB;            // 24 stripes
  const int batch  = unit / (NBANDB * NSTRIPB);        // 8 batches
  const int band0 = band * OBW;
  const int r0 = stripe * SHBR;

  const float2* ABb = AB + (size_t)batch * HH * WW;
  const float* sIb = sumI_ws + (size_t)batch * HH * WW;
  const float* Ib = I + (size_t)batch * CC * HH * WW;

  const int gc = band0 - RR + lane;                    // column this lane sums
  const bool colok = (gc >= 0 && gc < WW);
  const int oc = band0 + lane;                         // output col (lanes 0..47)
  const bool outok = (lane < OBW);
  const int nw = min(oc + RR, WW - 1) - max(oc - RR, 0) + 1;

  // warm-up: window of row r0-1 = rows [r0-9, r0+7] clipped
  float sA = 0.0f, sB = 0.0f;
  {
    int rlo = r0 - RR - 1; if (rlo < 0) rlo = 0;
    for (int row = rlo; row < r0 + RR; ++row) {
      if (colok) { float2 t = ABb[row * WW + gc]; sA += t.x; sB += t.y; }
    }
  }

  for (int r = r0; r < r0 + SHBR; ++r) {
    if (colok) {
      int rl = r + RR;
      if (rl < HH) { float2 t = ABb[rl * WW + gc]; sA += t.x; sB += t.y; }
      int rt = r - RR - 1;
      if (rt >= 0)  { float2 t = ABb[rt * WW + gc]; sA -= t.x; sB -= t.y; }
    }
    // horizontal 17-tap via shuffles (all lanes execute; results valid for lane<48)
    float a1 = __shfl_down(sA, 1), a2 = __shfl_down(sA, 2), a3 = __shfl_down(sA, 3);
    float b1 = __shfl_down(sB, 1), b2 = __shfl_down(sB, 2), b3 = __shfl_down(sB, 3);
    float s4A = sA + a1 + a2 + a3;
    float s4B = sB + b1 + b2 + b3;
    float hA = s4A + __shfl_down(s4A, 4) + __shfl_down(s4A, 8) + __shfl_down(s4A, 12)
             + __shfl_down(sA, 16);
    float hB = s4B + __shfl_down(s4B, 4) + __shfl_down(s4B, 8) + __shfl_down(s4B, 12)
             + __shfl_down(sB, 16);
    if (outok) {
      const int nh = min(r + RR, HH - 1) - max(r - RR, 0) + 1;
      const float invN = 1.0f / (float)(nh * nw);
      float sumI;
      if (useSum) {
        sumI = sIb[r * WW + oc];
      } else {
        const int off = r * WW + oc;
        const int chs = HH * WW;
        sumI = Ib[off] + Ib[chs + off] + Ib[2 * chs + off] + Ib[3 * chs + off];
      }
      q[((size_t)batch * HH + r) * WW + oc] = (hA * sumI + hB) * invN;
    }
  }
}

extern "C" void kernel_launch(void* const* d_in, const int* in_sizes, int n_in,
                              void* d_out, int out_size, void* d_ws, size_t ws_size,
                              hipStream_t stream) {
  const float* I = (const float*)d_in[0];   // (8,4,768,768) f32
  const float* p = (const float*)d_in[1];   // (8,1,768,768) f32
  float* q = (float*)d_out;                 // (8,1,768,768) f32

  const size_t npix = (size_t)BB * HH * WW;
  float2* AB = (float2*)d_ws;                               // 37.75 MB
  float* sumI_ws = (float*)(AB + npix);                     // +18.87 MB
  const size_t need = npix * sizeof(float2) + npix * sizeof(float);
  const int useSum = (ws_size >= need) ? 1 : 0;             // constant across calls

  dim3 gridA(NBAND, NSTRIPE, BB);
  dim3 gridB(UNITS / 4, 1, 1);              // 768 blocks x 4 waves
  dim3 blockA(TA);
  dim3 blockB(TBB);
  hipLaunchKernelGGL(gf_stageA, gridA, blockA, 0, stream, I, p, AB, sumI_ws, useSum);
  hipLaunchKernelGGL(gf_stageB, gridB, blockB, 0, stream, I, AB, sumI_ws, q, useSum);
}

// Round 9
// 231.044 us; speedup vs baseline: 1.0478x; 1.0478x over previous
//
#include <hip/hip_runtime.h>

// GuidedFilterND: I (8,4,768,768) f32 guide, p (8,1,768,768) f32 input, r=8, eps=1e-4.
// Stage A: box-filter 19 product channels, per-pixel 4x4 SPD solve -> (As,b) float2 + sumI (ws)
// Stage B: box-filter (As,b); q = (f(As)*sumI + f(b)) / N
// Round 9: stage A = round-5 exact (control, 111 us).  Stage B: same wave-synchronous
//          shuffle kernel as round 8 but at MAX occupancy — R3/R5/R6/R8 stage Bs all
//          ran at ~3-5 waves/SIMD (LDS-, VGPR-, or grid-capped) and all cost ~110-128 us
//          => latency-bound. SHBR 32->12 gives 8192 waves = 8/SIMD; loads burst in
//          4-row chunks; no LDS, no barriers, small VGPR.

#define HH 768
#define WW 768
#define CC 4
#define BB 8
#define RR 8
#define EPSF 1.0e-4f

#define TA 128      // stage A threads per block
#define OUTA 112    // output columns per block (TA - 2*RR)
#define SHA 24      // stage A rows per stripe
#define NSTRIPE (HH / SHA)    // 32
#define NBAND 7               // ceil(768/112)

// stage B wave geometry
#define OBW 48                // output columns per wave
#define NBANDB (WW / OBW)     // 16
#define SHBR 12               // rows per wave stripe (2.4x read amp, 8 waves/SIMD)
#define NSTRIPB (HH / SHBR)   // 64
#define UNITS (NBANDB * NSTRIPB * BB)   // 8192 wave-units
#define TBB 256               // 4 waves per block -> 2048 blocks

__device__ __forceinline__ void loadpix(const float* __restrict__ Ib,
                                        const float* __restrict__ pb,
                                        int row, int gc, float pr[19]) {
  const int off = row * WW + gc;
  const int chs = HH * WW;
  float i0 = Ib[off];
  float i1 = Ib[chs + off];
  float i2 = Ib[2 * chs + off];
  float i3 = Ib[3 * chs + off];
  float pv = pb[off];
  pr[0] = i0; pr[1] = i1; pr[2] = i2; pr[3] = i3;
  pr[4] = pv;
  pr[5] = pv * i0; pr[6] = pv * i1; pr[7] = pv * i2; pr[8] = pv * i3;
  pr[9]  = i0 * i0; pr[10] = i0 * i1; pr[11] = i0 * i2; pr[12] = i0 * i3;
  pr[13] = i1 * i1; pr[14] = i1 * i2; pr[15] = i1 * i3;
  pr[16] = i2 * i2; pr[17] = i2 * i3;
  pr[18] = i3 * i3;
}

__global__ __launch_bounds__(TA) void gf_stageA(const float* __restrict__ I,
                                                const float* __restrict__ p,
                                                float2* __restrict__ AB,
                                                float* __restrict__ sumI_ws,
                                                int storeSum) {
  // thread-major, padded to 20 floats (80 B): b128 accesses, conflict-free
  __shared__ float v[TA][20];
  __shared__ float s4[TA][20];
  const int tid = threadIdx.x;
  const int band0 = (int)blockIdx.x * OUTA;
  const int r0 = (int)blockIdx.y * SHA;
  const int batch = (int)blockIdx.z;
  const int gc = band0 - RR + tid;            // column this thread's vertical sum covers
  const bool colok = (gc >= 0 && gc < WW);

  const float* Ib = I + (size_t)batch * CC * HH * WW;
  const float* pb = p + (size_t)batch * HH * WW;
  float* sIb = sumI_ws + (size_t)batch * HH * WW;

  float s[20];
#pragma unroll
  for (int k = 0; k < 20; ++k) s[k] = 0.0f;

  // warm-up: preload window of row (r0-1) = rows [r0-RR-1, r0+RR-1] clipped.
  if (colok) {
    int rlo = r0 - RR - 1; if (rlo < 0) rlo = 0;
    for (int row = rlo; row < r0 + RR; ++row) {
      float pr[19]; loadpix(Ib, pb, row, gc, pr);
#pragma unroll
      for (int k = 0; k < 19; ++k) s[k] += pr[k];
      // rows 0..7 are only ever touched by stripe 0's warm-up: store sumI here
      if (storeSum && r0 == 0)
        sIb[row * WW + gc] = pr[0] + pr[1] + pr[2] + pr[3];
    }
  }

  const int oc = band0 + tid;                 // output column for threads < OUTA
  const bool outok = (tid < OUTA) && (oc < WW);
  const int nw = min(oc + RR, WW - 1) - max(oc - RR, 0) + 1;

  for (int r = r0; r < r0 + SHA; ++r) {
    if (colok) {
      int rl = r + RR;
      if (rl < HH) {
        float pr[19]; loadpix(Ib, pb, rl, gc, pr);
#pragma unroll
        for (int k = 0; k < 19; ++k) s[k] += pr[k];
        if (storeSum)
          sIb[rl * WW + gc] = pr[0] + pr[1] + pr[2] + pr[3];
      }
      int rt = r - RR - 1;
      if (rt >= 0) {
        float pr[19]; loadpix(Ib, pb, rt, gc, pr);
#pragma unroll
        for (int k = 0; k < 19; ++k) s[k] -= pr[k];
      }
    }
    // publish vertical sums: 5 x b128 writes
    {
      float4* vp = (float4*)(&v[tid][0]);
      vp[0] = make_float4(s[0],  s[1],  s[2],  s[3]);
      vp[1] = make_float4(s[4],  s[5],  s[6],  s[7]);
      vp[2] = make_float4(s[8],  s[9],  s[10], s[11]);
      vp[3] = make_float4(s[12], s[13], s[14], s[15]);
      vp[4] = make_float4(s[16], s[17], s[18], 0.0f);
    }
    __syncthreads();
    float t4[20];
    if (tid < TA - 3) {
      const float* a1 = &v[tid + 1][0];
      const float* a2 = &v[tid + 2][0];
      const float* a3 = &v[tid + 3][0];
      float4* op = (float4*)(&s4[tid][0]);
#pragma unroll
      for (int j = 0; j < 5; ++j) {
        float4 xa = ((const float4*)a1)[j];
        float4 xb = ((const float4*)a2)[j];
        float4 xc = ((const float4*)a3)[j];
        float o0 = s[4*j + 0] + xa.x + xb.x + xc.x;
        float o1 = s[4*j + 1] + xa.y + xb.y + xc.y;
        float o2 = s[4*j + 2] + xa.z + xb.z + xc.z;
        float o3 = s[4*j + 3] + xa.w + xb.w + xc.w;
        op[j] = make_float4(o0, o1, o2, o3);
        t4[4*j + 0] = o0; t4[4*j + 1] = o1; t4[4*j + 2] = o2; t4[4*j + 3] = o3;
      }
    }
    __syncthreads();
    if (outok) {
      float h[20];
      const float* q4  = &s4[tid + 4][0];
      const float* q8  = &s4[tid + 8][0];
      const float* q12 = &s4[tid + 12][0];
      const float* q16 = &v[tid + 16][0];
#pragma unroll
      for (int j = 0; j < 5; ++j) {
        float4 a4 = ((const float4*)q4)[j];
        float4 b4 = ((const float4*)q8)[j];
        float4 c4 = ((const float4*)q12)[j];
        float4 d4 = ((const float4*)q16)[j];
        h[4*j + 0] = t4[4*j + 0] + a4.x + b4.x + c4.x + d4.x;
        h[4*j + 1] = t4[4*j + 1] + a4.y + b4.y + c4.y + d4.y;
        h[4*j + 2] = t4[4*j + 2] + a4.z + b4.z + c4.z + d4.z;
        h[4*j + 3] = t4[4*j + 3] + a4.w + b4.w + c4.w + d4.w;
      }
      const int nh = min(r + RR, HH - 1) - max(r - RR, 0) + 1;
      const float invN = 1.0f / (float)(nh * nw);
      float Im0 = h[0] * invN, Im1 = h[1] * invN, Im2 = h[2] * invN, Im3 = h[3] * invN;
      float pm = h[4] * invN;
      float ft0 = h[5] * invN - pm * Im0;
      float ft1 = h[6] * invN - pm * Im1;
      float ft2 = h[7] * invN - pm * Im2;
      float ft3 = h[8] * invN - pm * Im3;
      float m[4][4];
      m[0][0] = h[9]  * invN + EPSF;
      m[0][1] = h[10] * invN;
      m[0][2] = h[11] * invN;
      m[0][3] = h[12] * invN;
      m[1][1] = h[13] * invN + EPSF;
      m[1][2] = h[14] * invN;
      m[1][3] = h[15] * invN;
      m[2][2] = h[16] * invN + EPSF;
      m[2][3] = h[17] * invN;
      m[3][3] = h[18] * invN + EPSF;
      m[1][0] = m[0][1]; m[2][0] = m[0][2]; m[3][0] = m[0][3];
      m[2][1] = m[1][2]; m[3][1] = m[1][3]; m[3][2] = m[2][3];
      float y[4] = {1.0f, 1.0f, 1.0f, 1.0f};
#pragma unroll
      for (int k = 0; k < 4; ++k) {
        float piv = 1.0f / m[k][k];
#pragma unroll
        for (int j = 0; j < 4; ++j) m[k][j] *= piv;
        y[k] *= piv;
#pragma unroll
        for (int i = 0; i < 4; ++i) {
          if (i == k) continue;
          float f = m[i][k];
#pragma unroll
          for (int j = 0; j < 4; ++j) m[i][j] -= f * m[k][j];
          y[i] -= f * y[k];
        }
      }
      float Asum = ft0 * y[0] + ft1 * y[1] + ft2 * y[2] + ft3 * y[3];
      float bv = pm - Asum * (Im0 + Im1 + Im2 + Im3);
      AB[((size_t)batch * HH + r) * WW + oc] = make_float2(Asum, bv);
    }
    __syncthreads();
  }
}

// Stage B: barrier-free wave-synchronous box filter at max occupancy.
// One wave owns a 48-col x 12-row output stripe; lane l carries the vertical
// rolling sum of column band0-8+l; horizontal 17-tap via cross-lane shuffles.
// Loads are burst in 4-row chunks for MLP; ~55 VGPR target -> 8 waves/SIMD.
__global__ __launch_bounds__(TBB) void gf_stageB(const float* __restrict__ I,
                                                 const float2* __restrict__ AB,
                                                 const float* __restrict__ sumI_ws,
                                                 float* __restrict__ q, int useSum) {
  const int lane = threadIdx.x & 63;
  const int wid  = threadIdx.x >> 6;
  const int unit = (int)blockIdx.x * 4 + wid;          // 0..UNITS-1
  const int band   = unit & (NBANDB - 1);              // 16 bands
  const int stripe = (unit >> 4) % NSTRIPB;            // 64 stripes
  const int batch  = unit / (NBANDB * NSTRIPB);        // 8 batches
  const int band0 = band * OBW;
  const int r0 = stripe * SHBR;

  const float2* ABb = AB + (size_t)batch * HH * WW;
  const float* sIb = sumI_ws + (size_t)batch * HH * WW;
  const float* Ib = I + (size_t)batch * CC * HH * WW;

  const int gc = band0 - RR + lane;                    // column this lane sums
  const bool colok = (gc >= 0 && gc < WW);
  const int oc = band0 + lane;                         // output col (lanes 0..47)
  const bool outok = (lane < OBW);
  const int nw = min(oc + RR, WW - 1) - max(oc - RR, 0) + 1;

  // warm-up: window of row r0-1 = rows [r0-9, r0+7] clipped; 17 independent loads
  float sA = 0.0f, sB = 0.0f;
#pragma unroll
  for (int k = 0; k < 17; ++k) {
    const int row = r0 - RR - 1 + k;
    if (row >= 0) {                                    // wave-uniform; row < HH always
      float2 t = colok ? ABb[row * WW + gc] : make_float2(0.0f, 0.0f);
      sA += t.x; sB += t.y;
    }
  }

#pragma unroll
  for (int c = 0; c < SHBR / 4; ++c) {                 // 3 chunks of 4 rows
    float2 wa[4], wb[4];
    float sm4[4];
#pragma unroll
    for (int j = 0; j < 4; ++j) {                      // burst: up to 12 loads in flight
      const int r = r0 + c * 4 + j;
      const int rl = r + RR;
      wa[j] = (rl < HH && colok) ? ABb[rl * WW + gc] : make_float2(0.0f, 0.0f);
      const int rt = r - RR - 1;
      wb[j] = (rt >= 0 && colok) ? ABb[rt * WW + gc] : make_float2(0.0f, 0.0f);
      if (useSum) sm4[j] = outok ? sIb[r * WW + oc] : 0.0f;
    }
#pragma unroll
    for (int j = 0; j < 4; ++j) {
      const int r = r0 + c * 4 + j;
      sA += wa[j].x - wb[j].x;
      sB += wa[j].y - wb[j].y;
      // horizontal 17-tap via shuffles (valid for lane < 48)
      float a1 = __shfl_down(sA, 1), a2 = __shfl_down(sA, 2), a3 = __shfl_down(sA, 3);
      float b1 = __shfl_down(sB, 1), b2 = __shfl_down(sB, 2), b3 = __shfl_down(sB, 3);
      float s4A = sA + a1 + a2 + a3;
      float s4B = sB + b1 + b2 + b3;
      float hA = s4A + __shfl_down(s4A, 4) + __shfl_down(s4A, 8) + __shfl_down(s4A, 12)
               + __shfl_down(sA, 16);
      float hB = s4B + __shfl_down(s4B, 4) + __shfl_down(s4B, 8) + __shfl_down(s4B, 12)
               + __shfl_down(sB, 16);
      if (outok) {
        const int nh = min(r + RR, HH - 1) - max(r - RR, 0) + 1;
        const float invN = 1.0f / (float)(nh * nw);
        float sumI;
        if (useSum) {
          sumI = sm4[j];
        } else {
          const int off = r * WW + oc;
          const int chs = HH * WW;
          sumI = Ib[off] + Ib[chs + off] + Ib[2 * chs + off] + Ib[3 * chs + off];
        }
        q[((size_t)batch * HH + r) * WW + oc] = (hA * sumI + hB) * invN;
      }
    }
  }
}

extern "C" void kernel_launch(void* const* d_in, const int* in_sizes, int n_in,
                              void* d_out, int out_size, void* d_ws, size_t ws_size,
                              hipStream_t stream) {
  const float* I = (const float*)d_in[0];   // (8,4,768,768) f32
  const float* p = (const float*)d_in[1];   // (8,1,768,768) f32
  float* q = (float*)d_out;                 // (8,1,768,768) f32

  const size_t npix = (size_t)BB * HH * WW;
  float2* AB = (float2*)d_ws;                               // 37.75 MB
  float* sumI_ws = (float*)(AB + npix);                     // +18.87 MB
  const size_t need = npix * sizeof(float2) + npix * sizeof(float);
  const int useSum = (ws_size >= need) ? 1 : 0;             // constant across calls

  dim3 gridA(NBAND, NSTRIPE, BB);
  dim3 gridB(UNITS / 4, 1, 1);              // 2048 blocks x 4 waves = 8192 waves
  dim3 blockA(TA);
  dim3 blockB(TBB);
  hipLaunchKernelGGL(gf_stageA, gridA, blockA, 0, stream, I, p, AB, sumI_ws, useSum);
  hipLaunchKernelGGL(gf_stageB, gridB, blockB, 0, stream, I, AB, sumI_ws, q, useSum);
}